// Round 7
// baseline (583.844 us; speedup 1.0000x reference)
//
#include <hip/hip_runtime.h>

#define TT 512    // max sequence length T
#define NN 128    // number of tags N
#define NTHR 1024 // 16 waves, 4 per SIMD
#define BD  64    // backtrack chunk depth
#define MAXG 8    // max chunks = ceil((TT-1)/BD)
#define SROW 192  // swizzled state row: 16 chunks x 12 floats (8 used + 4 pad)
#define SW8(i) (12 * ((i) >> 3) + ((i) & 7))

// Barrier WITHOUT vmcnt drain: LDS writes drained, global prefetches stay
// in flight (compiler inserts vmcnt waits at use).
#define STEP_BARRIER() asm volatile("s_waitcnt lgkmcnt(0)\n\ts_barrier" ::: "memory")

// DPP cross-lane (pure VALU, no LDS pipe)
template <int CTRL>
__device__ __forceinline__ int dpp_i(int x) {
    return __builtin_amdgcn_update_dpp(x, x, CTRL, 0xf, 0xf, true);
}
template <int CTRL>
__device__ __forceinline__ float dpp_f(float x) {
    union { float f; int i; } u; u.f = x;
    u.i = dpp_i<CTRL>(u.i);
    return u.f;
}
#define DPP_XOR1  0xB1   // quad_perm [1,0,3,2]          : lane ^= 1
#define DPP_XOR2  0x4E   // quad_perm [2,3,0,1]          : lane ^= 2
#define DPP_MIR7  0x141  // row_half_mirror (lane ^= 7)  : == ^4 after 1,2
#define DPP_MIR15 0x140  // row_mirror      (lane ^= 15) : == ^8 after 1,2,4

// One block per batch element (256 blocks <-> 256 CUs), 1024 threads.
// thread -> (j, c): j = tid>>4 (serves tags j and j+64), c = tid&15 owns
// i-range [8c, 8c+8). trans in VGPRs (16/thread). State double-buffered in
// LDS, stride-12 chunk swizzle (16 bases tile 32 banks exactly 2-way = free).
// 2 sub-chain streaming argmax + 4-stage all-DPP merge. lgkm-only barrier.
__global__ __launch_bounds__(NTHR, 1)
void crf_viterbi_kernel(const float* __restrict__ logits,
                        const float* __restrict__ trans,
                        const int* __restrict__ seqlen,
                        int* __restrict__ out) {
    __shared__ float stateBuf[2][SROW];
    __shared__ float redV[NN];
    __shared__ int   redI[NN];
    __shared__ int   tagBuf[TT];
    __shared__ int   entryTag[MAXG];
    __shared__ unsigned char bp[TT][NN];          // 64 KiB backpointers
    __shared__ unsigned char hist[MAXG][BD][NN];  // 64 KiB backtrack histories

    const int tid = threadIdx.x;
    const int j   = tid >> 4;   // 0..63 (serves j and j+64)
    const int c   = tid & 15;   // i-chunk
    const int i0  = c << 3;
    const int b   = blockIdx.x;
    const int L   = seqlen[b];  // in [1, TT]
    const int jx  = j + ((c & 1) << 6);  // the tag whose x this lane loads

    // Transition chunks: tr0[k] = trans[i0+k][j], tr1[k] = trans[i0+k][j+64]
    float tr0[8], tr1[8];
    #pragma unroll
    for (int k = 0; k < 8; ++k) {
        tr0[k] = trans[(i0 + k) * NN + j];
        tr1[k] = trans[(i0 + k) * NN + j + 64];
    }

    const float* lrow = logits + (size_t)b * TT * NN;

    // t = 0 init (swizzled layout); writers are lanes c==0 (tag j), c==1 (j+64)
    if (c < 2) stateBuf[0][SW8(jx)] = lrow[jx];
    __syncthreads();

    // xa = x[t][jx] for the current step t (only consumed by lanes c<2)
    float xa = lrow[NN + jx];

    // One Viterbi step: read src, write dst, consume xa, prefetch next x.
    auto vstep = [&](const float* st, float* dst, int t) {
        int tn = t + 1; tn = (tn < TT) ? tn : (TT - 1);
        float xnext = lrow[tn * NN + jx];

        const float* sp = st + 12 * c;
        float4 a0 = *(const float4*)(sp);
        float4 a1 = *(const float4*)(sp + 4);

        // Two independent 4-long sub-chains per tag (short serial chain),
        // strict > over ascending k == first-occurrence.
        float bA0 = -__builtin_inff(), bB0 = -__builtin_inff();
        float bA1 = -__builtin_inff(), bB1 = -__builtin_inff();
        int aA0 = 0, aB0 = 4, aA1 = 0, aB1 = 4;
        #define ELEM(S, K, BV0, AR0, BV1, AR1)                                 \
        {                                                                      \
            float sc = (S) + tr0[K];                                           \
            bool g = sc > BV0; BV0 = g ? sc : BV0; AR0 = g ? (K) : AR0;        \
            float sd = (S) + tr1[K];                                           \
            bool h = sd > BV1; BV1 = h ? sd : BV1; AR1 = h ? (K) : AR1;        \
        }
        ELEM(a0.x, 0, bA0, aA0, bA1, aA1)
        ELEM(a0.y, 1, bA0, aA0, bA1, aA1)
        ELEM(a0.z, 2, bA0, aA0, bA1, aA1)
        ELEM(a0.w, 3, bA0, aA0, bA1, aA1)
        ELEM(a1.x, 4, bB0, aB0, bB1, aB1)
        ELEM(a1.y, 5, bB0, aB0, bB1, aB1)
        ELEM(a1.z, 6, bB0, aB0, bB1, aB1)
        ELEM(a1.w, 7, bB0, aB0, bB1, aB1)
        #undef ELEM
        // combine sub-chains (A indices < B indices: take B only if strictly >)
        bool gc0 = bB0 > bA0, gc1 = bB1 > bA1;
        float bv0 = gc0 ? bB0 : bA0, bv1 = gc1 ? bB1 : bA1;
        int   bi0 = i0 + (gc0 ? aB0 : aA0), bi1 = i0 + (gc1 ? aB1 : aA1);

        // 4-stage all-DPP merge across the 16 lanes of this tag pair.
        // Tie -> lower chunk wins (exact first-occurrence).
        #define MERGE_STAGE(CTRL, LOWER)                                   \
        {                                                                  \
            float p0 = dpp_f<CTRL>(bv0); int q0 = dpp_i<CTRL>(bi0);        \
            float p1 = dpp_f<CTRL>(bv1); int q1 = dpp_i<CTRL>(bi1);        \
            bool lower = (LOWER);                                          \
            bool t0 = (p0 > bv0) || (p0 == bv0 && lower);                  \
            bool t1 = (p1 > bv1) || (p1 == bv1 && lower);                  \
            bv0 = t0 ? p0 : bv0; bi0 = t0 ? q0 : bi0;                      \
            bv1 = t1 ? p1 : bv1; bi1 = t1 ? q1 : bi1;                      \
        }
        MERGE_STAGE(DPP_XOR1,  (c & 1) != 0)
        MERGE_STAGE(DPP_XOR2,  (c & 2) != 0)
        MERGE_STAGE(DPP_MIR7,  (c & 4) != 0)
        MERGE_STAGE(DPP_MIR15, (c & 8) != 0)
        #undef MERGE_STAGE

        if (c < 2) {   // c==0 writes tag j, c==1 writes tag j+64
            float bv = c ? bv1 : bv0;
            int   bi = c ? bi1 : bi0;
            dst[SW8(jx)] = bv + xa;
            bp[t][jx] = (unsigned char)bi;
        }
        xa = xnext;
        STEP_BARRIER();
    };

    // Unrolled-by-2 main loop: compile-time LDS buffer pointers.
    int t = 1;
    for (; t + 1 < L; t += 2) {
        vstep(stateBuf[0], stateBuf[1], t);
        vstep(stateBuf[1], stateBuf[0], t + 1);
    }
    if (t < L) vstep(stateBuf[0], stateBuf[1], t);

    __syncthreads();   // full drain before epilogue
    const int pf = (L - 1) & 1;   // buffer holding the final state

    // Final argmax over state (first-occurrence: min index on ties).
    if (tid < NN) { redV[tid] = stateBuf[pf][SW8(tid)]; redI[tid] = tid; }
    __syncthreads();
    #pragma unroll
    for (int off = 64; off >= 1; off >>= 1) {
        if (tid < off) {
            float va = redV[tid], vb = redV[tid + off];
            int   ia = redI[tid], ib = redI[tid + off];
            if (vb > va || (vb == va && ib < ia)) { redV[tid] = vb; redI[tid] = ib; }
        }
        __syncthreads();
    }

    // ---- Parallel backtrack via chunked function composition ----
    const int M = L - 1;
    const int G = (M + BD - 1) / BD;   // 0..8

    {   // pass 1: one (chunk, entry-tag) per thread
        int s = tid & 127;
        int g = tid >> 7;              // 0..7
        if (g < G) {
            int th  = M - g * BD;
            int dep = (th < BD) ? th : BD;
            int cur = s;
            for (int d = 0; d < dep; ++d) {
                cur = bp[th - d][cur];
                hist[g][d][s] = (unsigned char)cur;
            }
        }
    }
    __syncthreads();

    if (tid == 0) {   // entry-tag scan across chunks (G <= 8 serial lookups)
        int e = redI[0];
        tagBuf[L - 1] = e;
        for (int g = 0; g < G; ++g) {
            entryTag[g] = e;
            if (g + 1 < G) e = hist[g][BD - 1][e];   // chunks < G-1 are full
        }
    }
    __syncthreads();

    {   // pass 2: copy winning histories into tagBuf
        int g = tid >> 6, d = tid & 63;
        if (g < G) {                   // g in 0..15; only g < G active
            int th  = M - g * BD;
            int dep = (th < BD) ? th : BD;
            if (d < dep) {
                int e = entryTag[g];
                tagBuf[th - 1 - d] = hist[g][d][e];
            }
        }
    }
    __syncthreads();

    // Coalesced output: tags for k < L, zeros for the masked tail.
    if (tid < TT) {
        int* orow = out + (size_t)b * TT;
        orow[tid] = (tid < L) ? tagBuf[tid] : 0;
    }
}

extern "C" void kernel_launch(void* const* d_in, const int* in_sizes, int n_in,
                              void* d_out, int out_size, void* d_ws, size_t ws_size,
                              hipStream_t stream) {
    const float* logits = (const float*)d_in[0];
    const float* trans  = (const float*)d_in[1];
    const int*   seqlen = (const int*)d_in[2];
    int*         out    = (int*)d_out;
    const int B = in_sizes[2];  // 256
    crf_viterbi_kernel<<<B, NTHR, 0, stream>>>(logits, trans, seqlen, out);
}